// Round 2
// baseline (844.036 us; speedup 1.0000x reference)
//
#include <hip/hip_runtime.h>
#include <float.h>
#include <math.h>

#define C    1024
#define NQ   10
#define K1T  64    // rows per k1 block (1 wave, thread-per-row)
#define G4   512   // K4 grid

// ---------------- K0: qd[k] = Qn[k] - Qn[NQ]  (normalize 11 query rows) ----
__global__ __launch_bounds__(256) void k0_qdiff(const float* __restrict__ Q,
                                                float* __restrict__ qd) {
  __shared__ float red[256];
  __shared__ float inorm[NQ + 1];
  int t = threadIdx.x;
  for (int k = 0; k <= NQ; ++k) {
    float s = 0.f;
    for (int c = t; c < C; c += 256) { float v = Q[k * C + c]; s = fmaf(v, v, s); }
    red[t] = s; __syncthreads();
    for (int st = 128; st > 0; st >>= 1) {
      if (t < st) red[t] += red[t + st];
      __syncthreads();
    }
    if (t == 0) inorm[k] = 1.0f / fmaxf(sqrtf(red[0]), 1e-12f);
    __syncthreads();
  }
  for (int k = 0; k < NQ; ++k)
    for (int c = t; c < C; c += 256)
      qd[k * C + c] = Q[k * C + c] * inorm[k] - Q[NQ * C + c] * inorm[NQ];
}

// ---------------- K1: logits L[k][n] = 100 * (qd_k . x_n) / ||x_n||  -------
// 1-wave blocks, thread-per-row. X read per-thread-row (L1/L2 absorbs the
// scatter; one addr reg + imm offsets). q comes from SGPRs: qd indices are
// wave-uniform -> s_load; fma reads 1 SGPR operand. Zero LDS, zero barriers.
__global__ __launch_bounds__(64) void k1_logits(const float* __restrict__ X,
                                                const float* __restrict__ qd,
                                                float* __restrict__ Lg,
                                                float* __restrict__ maxp, int N) {
  int t = threadIdx.x;
  int row = blockIdx.x * K1T + t;
  const float* p = X + (size_t)(row < N ? row : N - 1) * C;

  float dot[NQ];
#pragma unroll
  for (int k = 0; k < NQ; ++k) dot[k] = 0.f;
  float ss = 0.f;

#pragma unroll 8
  for (int g = 0; g < C / 4; ++g) {
    float4 xv = *(const float4*)(p + (g << 2));
    ss = fmaf(xv.x, xv.x, fmaf(xv.y, xv.y, fmaf(xv.z, xv.z, fmaf(xv.w, xv.w, ss))));
#pragma unroll
    for (int k = 0; k < NQ; ++k) {
      const float4 q4 = *(const float4*)(qd + k * C + (g << 2));  // uniform -> s_load
      dot[k] = fmaf(xv.x, q4.x, fmaf(xv.y, q4.y, fmaf(xv.z, q4.z, fmaf(xv.w, q4.w, dot[k]))));
    }
  }

  bool act = row < N;
  float rn = 1.0f / fmaxf(sqrtf(ss), 1e-12f);
#pragma unroll
  for (int k = 0; k < NQ; ++k) {
    float lg = act ? (100.0f * dot[k] * rn) : -FLT_MAX;
    if (act) Lg[(size_t)k * N + row] = lg;
    float m = lg;
#pragma unroll
    for (int off = 32; off > 0; off >>= 1) m = fmaxf(m, __shfl_down(m, off));
    if (t == 0) maxp[blockIdx.x * NQ + k] = m;
  }
}

// ---------------- K2: global max per query ---------------------------------
__global__ __launch_bounds__(256) void k2_gmax(const float* __restrict__ maxp,
                                               float* __restrict__ M, int TILES) {
  __shared__ float red[256];
  int t = threadIdx.x;
  for (int k = 0; k < NQ; ++k) {
    float mm = -FLT_MAX;
    for (int i = t; i < TILES; i += 256) mm = fmaxf(mm, maxp[i * NQ + k]);
    red[t] = mm; __syncthreads();
    for (int st = 128; st > 0; st >>= 1) {
      if (t < st) red[t] = fmaxf(red[t], red[t + st]);
      __syncthreads();
    }
    if (t == 0) M[k] = red[0];
    __syncthreads();
  }
}

// ---------------- K4: per-block partial weighted sums + partial denoms -----
__global__ __launch_bounds__(256) void k4_partial(const float* __restrict__ X,
                                                  const float* __restrict__ Lg,
                                                  const float* __restrict__ M,
                                                  float* __restrict__ partial,
                                                  float* __restrict__ dsum,
                                                  int N, int rpb) {
  int g = blockIdx.x, t = threadIdx.x;
  int n0 = g * rpb;
  int n1 = min(n0 + rpb, N);
  float m[NQ];
#pragma unroll
  for (int k = 0; k < NQ; ++k) m[k] = M[k];
  float a[NQ][4];
#pragma unroll
  for (int k = 0; k < NQ; ++k) { a[k][0] = 0.f; a[k][1] = 0.f; a[k][2] = 0.f; a[k][3] = 0.f; }
  float ds[NQ];
#pragma unroll
  for (int k = 0; k < NQ; ++k) ds[k] = 0.f;

#pragma unroll 2
  for (int n = n0; n < n1; ++n) {
    float4 x4 = *(const float4*)&X[(size_t)n * C + (t << 2)];
    float w[NQ];
#pragma unroll
    for (int k = 0; k < NQ; ++k) w[k] = __expf(Lg[(size_t)k * N + n] - m[k]);  // uniform -> s_load
#pragma unroll
    for (int k = 0; k < NQ; ++k) {
      ds[k] += w[k];
      a[k][0] = fmaf(w[k], x4.x, a[k][0]);
      a[k][1] = fmaf(w[k], x4.y, a[k][1]);
      a[k][2] = fmaf(w[k], x4.z, a[k][2]);
      a[k][3] = fmaf(w[k], x4.w, a[k][3]);
    }
  }
#pragma unroll
  for (int k = 0; k < NQ; ++k) {
    float4 o; o.x = a[k][0]; o.y = a[k][1]; o.z = a[k][2]; o.w = a[k][3];
    *(float4*)&partial[(((size_t)(g * NQ + k)) << 10) + (t << 2)] = o;
  }
  if (t == 0) {
#pragma unroll
    for (int k = 0; k < NQ; ++k) dsum[g * NQ + k] = ds[k];
  }
}

// ---------------- K5a: pooled[c] = sum_k sum_g partial/(10*D_k) ------------
__global__ __launch_bounds__(256) void k5a_pooled(const float* __restrict__ partial,
                                                  const float* __restrict__ dsum,
                                                  float* __restrict__ pooled) {
  __shared__ float invD[NQ];
  __shared__ float r4[256][4];
  int t = threadIdx.x;
  if (t < NQ) {
    float s = 0.f;
    for (int g = 0; g < G4; ++g) s += dsum[g * NQ + t];
    invD[t] = 1.0f / (s * (float)NQ);
  }
  __syncthreads();
  int c0 = blockIdx.x * 4;
  float a0 = 0.f, a1 = 0.f, a2 = 0.f, a3 = 0.f;
  for (int idx = t; idx < G4 * NQ; idx += 256) {
    int k = idx % NQ;
    const float4 p = *(const float4*)&partial[(((size_t)idx) << 10) + c0];
    float s = invD[k];
    a0 = fmaf(p.x, s, a0); a1 = fmaf(p.y, s, a1);
    a2 = fmaf(p.z, s, a2); a3 = fmaf(p.w, s, a3);
  }
  r4[t][0] = a0; r4[t][1] = a1; r4[t][2] = a2; r4[t][3] = a3;
  __syncthreads();
  for (int st = 128; st > 0; st >>= 1) {
    if (t < st) {
      r4[t][0] += r4[t + st][0]; r4[t][1] += r4[t + st][1];
      r4[t][2] += r4[t + st][2]; r4[t][3] += r4[t + st][3];
    }
    __syncthreads();
  }
  if (t < 4) pooled[c0 + t] = r4[0][t];
}

// ---------------- K5b: out[j] = b[j] + sum_c pooled[c] * W[j][c] -----------
__global__ __launch_bounds__(256) void k5b_out(const float* __restrict__ W,
                                               const float* __restrict__ bias,
                                               const float* __restrict__ pooled,
                                               float* __restrict__ out) {
  __shared__ float sp[C];
  int t = threadIdx.x;
  for (int i = t; i < C; i += 256) sp[i] = pooled[i];
  __syncthreads();
  int wv = t >> 6, lane = t & 63;
#pragma unroll
  for (int jj = 0; jj < 8; ++jj) {
    int j = blockIdx.x * 32 + wv * 8 + jj;
    float s = 0.f;
#pragma unroll
    for (int seg = 0; seg < 4; ++seg) {
      int cbase = seg * 256 + lane * 4;
      float4 w4 = *(const float4*)&W[(size_t)j * C + cbase];
      float4 p4 = *(const float4*)&sp[cbase];
      s += w4.x * p4.x + w4.y * p4.y + w4.z * p4.z + w4.w * p4.w;
    }
#pragma unroll
    for (int off = 32; off > 0; off >>= 1) s += __shfl_down(s, off);
    if (lane == 0) out[j] = s + bias[j];
  }
}

// ---------------------------------------------------------------------------
extern "C" void kernel_launch(void* const* d_in, const int* in_sizes, int n_in,
                              void* d_out, int out_size, void* d_ws, size_t ws_size,
                              hipStream_t stream) {
  const float* X = (const float*)d_in[0];
  const float* Q = (const float*)d_in[1];
  const float* W = (const float*)d_in[2];
  const float* b = (const float*)d_in[3];
  float* out = (float*)d_out;

  int N = in_sizes[0] / C;                 // 100000
  int TILES = (N + K1T - 1) / K1T;         // 1563
  int rpb = (N + G4 - 1) / G4;             // 196

  float* ws      = (float*)d_ws;
  float* qd      = ws;                               // NQ*C
  float* M       = qd + NQ * C;                      // 16 (padded)
  float* maxp    = M + 16;                           // TILES*NQ
  float* dsum    = maxp + ((TILES * NQ + 15) & ~15); // G4*NQ
  float* pooled  = dsum + G4 * NQ;                   // C
  float* Lg      = pooled + C;                       // NQ*N
  float* partial = Lg + (size_t)NQ * N;              // G4*NQ*C  (~20 MB)

  hipLaunchKernelGGL(k0_qdiff,  dim3(1),      dim3(256), 0, stream, Q, qd);
  hipLaunchKernelGGL(k1_logits, dim3(TILES),  dim3(64),  0, stream, X, qd, Lg, maxp, N);
  hipLaunchKernelGGL(k2_gmax,   dim3(1),      dim3(256), 0, stream, maxp, M, TILES);
  hipLaunchKernelGGL(k4_partial,dim3(G4),     dim3(256), 0, stream, X, Lg, M, partial, dsum, N, rpb);
  hipLaunchKernelGGL(k5a_pooled,dim3(C / 4),  dim3(256), 0, stream, partial, dsum, pooled);
  hipLaunchKernelGGL(k5b_out,   dim3(C / 32), dim3(256), 0, stream, W, b, pooled, out);
}

// Round 4
// 749.562 us; speedup vs baseline: 1.1260x; 1.1260x over previous
//
#include <hip/hip_runtime.h>
#include <float.h>
#include <math.h>

#define C    1024
#define NQ   10
#define LGS  16        // Lg row stride (floats): one 64B line per row
#define K1B  2048      // k1 blocks (x4 waves = 8192 waves)
#define K1W  (K1B * 4)
#define G4   512       // K4 grid

// ---- wave64 sum via DPP (pure VALU; avoids ds_swizzle LDS-pipe cost) ------
template <int CTRL, int ROWM>
__device__ __forceinline__ float dpp_add(float x) {
  int mv = __builtin_amdgcn_update_dpp(0, __float_as_int(x), CTRL, ROWM, 0xf, true);
  return x + __int_as_float(mv);
}
__device__ __forceinline__ float wave_sum64(float x) {
  x = dpp_add<0xB1,  0xf>(x);  // quad_perm [1,0,3,2]  (xor 1)
  x = dpp_add<0x4E,  0xf>(x);  // quad_perm [2,3,0,1]  (xor 2)
  x = dpp_add<0x141, 0xf>(x);  // row_half_mirror      (xor-pair 4)
  x = dpp_add<0x140, 0xf>(x);  // row_mirror           (xor-pair 8)
  x = dpp_add<0x142, 0xa>(x);  // row_bcast15 -> rows 1,3
  x = dpp_add<0x143, 0xc>(x);  // row_bcast31 -> rows 2,3
  return __int_as_float(__builtin_amdgcn_readlane(__float_as_int(x), 63));
}

// ---------------- K0: qd[k] = Qn[k] - Qn[NQ] -------------------------------
__global__ __launch_bounds__(256) void k0_qdiff(const float* __restrict__ Q,
                                                float* __restrict__ qd) {
  __shared__ float red[256];
  __shared__ float inorm[NQ + 1];
  int t = threadIdx.x;
  for (int k = 0; k <= NQ; ++k) {
    float s = 0.f;
    for (int c = t; c < C; c += 256) { float v = Q[k * C + c]; s = fmaf(v, v, s); }
    red[t] = s; __syncthreads();
    for (int st = 128; st > 0; st >>= 1) {
      if (t < st) red[t] += red[t + st];
      __syncthreads();
    }
    if (t == 0) inorm[k] = 1.0f / fmaxf(sqrtf(red[0]), 1e-12f);
    __syncthreads();
  }
  for (int k = 0; k < NQ; ++k)
    for (int c = t; c < C; c += 256)
      qd[k * C + c] = Q[k * C + c] * inorm[k] - Q[NQ * C + c] * inorm[NQ];
}

// ---------------- K1: wave-per-row logits ----------------------------------
// Coalesced: 64 lanes span one 4KB row (4x dwordx4 = 1KB/instr). q fragments
// in VGPRs (160), loaded once per wave from L2-resident qd. Cross-lane sums
// via DPP (VALU pipe). Lg row-major [row][16] -> 1 line/row for k4 s_loads.
__global__ __launch_bounds__(256) void k1_logits(const float* __restrict__ X,
                                                 const float* __restrict__ qd,
                                                 float* __restrict__ Lg,
                                                 float* __restrict__ bmax,
                                                 int N) {
  const int t  = threadIdx.x;
  const int l  = t & 63, wv = t >> 6;
  const int w  = blockIdx.x * 4 + wv;      // global wave id
  const int co = l << 2;                   // lane column offset

  float4 q4[NQ][4];
#pragma unroll
  for (int k = 0; k < NQ; ++k)
#pragma unroll
    for (int j = 0; j < 4; ++j)
      q4[k][j] = *(const float4*)(qd + k * C + j * 256 + co);

  float mx[NQ];
#pragma unroll
  for (int k = 0; k < NQ; ++k) mx[k] = -FLT_MAX;

  for (int r = w; r < N; r += K1W) {       // wave-uniform trip count
    const float* xp = X + (size_t)r * C + co;
    float4 xv[4];
#pragma unroll
    for (int j = 0; j < 4; ++j) xv[j] = *(const float4*)(xp + j * 256);

    float ss = 0.f;
    float dot[NQ];
#pragma unroll
    for (int k = 0; k < NQ; ++k) dot[k] = 0.f;
#pragma unroll
    for (int j = 0; j < 4; ++j) {
      float4 v = xv[j];
      ss = fmaf(v.x, v.x, fmaf(v.y, v.y, fmaf(v.z, v.z, fmaf(v.w, v.w, ss))));
#pragma unroll
      for (int k = 0; k < NQ; ++k) {
        float4 q = q4[k][j];
        dot[k] = fmaf(v.x, q.x, fmaf(v.y, q.y, fmaf(v.z, q.z, fmaf(v.w, q.w, dot[k]))));
      }
    }

    float ssu = wave_sum64(ss);
    float rn  = 100.0f / fmaxf(sqrtf(ssu), 1e-12f);
    float lg[NQ];
#pragma unroll
    for (int k = 0; k < NQ; ++k) {
      lg[k] = wave_sum64(dot[k]) * rn;
      mx[k] = fmaxf(mx[k], lg[k]);
    }
    if (l == 0) {
      float* lp = Lg + (size_t)r * LGS;
      *(float4*)(lp)     = make_float4(lg[0], lg[1], lg[2], lg[3]);
      *(float4*)(lp + 4) = make_float4(lg[4], lg[5], lg[6], lg[7]);
      *(float2*)(lp + 8) = make_float2(lg[8], lg[9]);
    }
  }

  __shared__ float sm[4][16];
  if (l == 0) {
#pragma unroll
    for (int k = 0; k < NQ; ++k) sm[wv][k] = mx[k];
  }
  __syncthreads();
  if (t < NQ) {
    float m = fmaxf(fmaxf(sm[0][t], sm[1][t]), fmaxf(sm[2][t], sm[3][t]));
    bmax[blockIdx.x * 16 + t] = m;
  }
}

// ---------------- K2: global max per query (one block per k) ---------------
__global__ __launch_bounds__(256) void k2_gmax(const float* __restrict__ bmax,
                                               float* __restrict__ M, int NB) {
  __shared__ float red[256];
  int k = blockIdx.x, t = threadIdx.x;
  float mm = -FLT_MAX;
  for (int i = t; i < NB; i += 256) mm = fmaxf(mm, bmax[i * 16 + k]);
  red[t] = mm; __syncthreads();
  for (int st = 128; st > 0; st >>= 1) {
    if (t < st) red[t] = fmaxf(red[t], red[t + st]);
    __syncthreads();
  }
  if (t == 0) M[k] = red[0];
}

// ---------------- K4: per-block partial weighted sums + denoms -------------
__global__ __launch_bounds__(256) void k4_partial(const float* __restrict__ X,
                                                  const float* __restrict__ Lg,
                                                  const float* __restrict__ M,
                                                  float* __restrict__ partial,
                                                  float* __restrict__ dsum,
                                                  int N, int rpb) {
  int g = blockIdx.x, t = threadIdx.x;
  int n0 = g * rpb;
  int n1 = min(n0 + rpb, N);
  float m[NQ];
#pragma unroll
  for (int k = 0; k < NQ; ++k) m[k] = M[k];
  float a[NQ][4];
#pragma unroll
  for (int k = 0; k < NQ; ++k) { a[k][0] = 0.f; a[k][1] = 0.f; a[k][2] = 0.f; a[k][3] = 0.f; }
  float ds[NQ];
#pragma unroll
  for (int k = 0; k < NQ; ++k) ds[k] = 0.f;

#pragma unroll 2
  for (int n = n0; n < n1; ++n) {
    float4 x4 = *(const float4*)&X[(size_t)n * C + (t << 2)];
    float w[NQ];
#pragma unroll
    for (int k = 0; k < NQ; ++k) w[k] = __expf(Lg[(size_t)n * LGS + k] - m[k]);  // 1 line, s_load
#pragma unroll
    for (int k = 0; k < NQ; ++k) {
      ds[k] += w[k];
      a[k][0] = fmaf(w[k], x4.x, a[k][0]);
      a[k][1] = fmaf(w[k], x4.y, a[k][1]);
      a[k][2] = fmaf(w[k], x4.z, a[k][2]);
      a[k][3] = fmaf(w[k], x4.w, a[k][3]);
    }
  }
#pragma unroll
  for (int k = 0; k < NQ; ++k) {
    float4 o; o.x = a[k][0]; o.y = a[k][1]; o.z = a[k][2]; o.w = a[k][3];
    *(float4*)&partial[(((size_t)(g * NQ + k)) << 10) + (t << 2)] = o;
  }
  if (t == 0) {
#pragma unroll
    for (int k = 0; k < NQ; ++k) dsum[g * NQ + k] = ds[k];
  }
}

// ---------------- K5a: pooled[c] = sum_k sum_g partial/(10*D_k) ------------
__global__ __launch_bounds__(256) void k5a_pooled(const float* __restrict__ partial,
                                                  const float* __restrict__ dsum,
                                                  float* __restrict__ pooled) {
  __shared__ float invD[NQ];
  __shared__ float r4[256][4];
  int t = threadIdx.x;
  if (t < NQ) {
    float s = 0.f;
    for (int g = 0; g < G4; ++g) s += dsum[g * NQ + t];
    invD[t] = 1.0f / (s * (float)NQ);
  }
  __syncthreads();
  int c0 = blockIdx.x * 4;
  float a0 = 0.f, a1 = 0.f, a2 = 0.f, a3 = 0.f;
  for (int idx = t; idx < G4 * NQ; idx += 256) {
    int k = idx % NQ;
    const float4 p = *(const float4*)&partial[(((size_t)idx) << 10) + c0];
    float s = invD[k];
    a0 = fmaf(p.x, s, a0); a1 = fmaf(p.y, s, a1);
    a2 = fmaf(p.z, s, a2); a3 = fmaf(p.w, s, a3);
  }
  r4[t][0] = a0; r4[t][1] = a1; r4[t][2] = a2; r4[t][3] = a3;
  __syncthreads();
  for (int st = 128; st > 0; st >>= 1) {
    if (t < st) {
      r4[t][0] += r4[t + st][0]; r4[t][1] += r4[t + st][1];
      r4[t][2] += r4[t + st][2]; r4[t][3] += r4[t + st][3];
    }
    __syncthreads();
  }
  if (t < 4) pooled[c0 + t] = r4[0][t];
}

// ---------------- K5b: out[j] = b[j] + sum_c pooled[c] * W[j][c] -----------
__global__ __launch_bounds__(256) void k5b_out(const float* __restrict__ W,
                                               const float* __restrict__ bias,
                                               const float* __restrict__ pooled,
                                               float* __restrict__ out) {
  __shared__ float sp[C];
  int t = threadIdx.x;
  for (int i = t; i < C; i += 256) sp[i] = pooled[i];
  __syncthreads();
  int wv = t >> 6, lane = t & 63;
#pragma unroll
  for (int jj = 0; jj < 8; ++jj) {
    int j = blockIdx.x * 32 + wv * 8 + jj;
    float s = 0.f;
#pragma unroll
    for (int seg = 0; seg < 4; ++seg) {
      int cbase = seg * 256 + lane * 4;
      float4 w4 = *(const float4*)&W[(size_t)j * C + cbase];
      float4 p4 = *(const float4*)&sp[cbase];
      s += w4.x * p4.x + w4.y * p4.y + w4.z * p4.z + w4.w * p4.w;
    }
#pragma unroll
    for (int off = 32; off > 0; off >>= 1) s += __shfl_down(s, off);
    if (lane == 0) out[j] = s + bias[j];
  }
}

// ---------------------------------------------------------------------------
extern "C" void kernel_launch(void* const* d_in, const int* in_sizes, int n_in,
                              void* d_out, int out_size, void* d_ws, size_t ws_size,
                              hipStream_t stream) {
  const float* X = (const float*)d_in[0];
  const float* Q = (const float*)d_in[1];
  const float* W = (const float*)d_in[2];
  const float* b = (const float*)d_in[3];
  float* out = (float*)d_out;

  int N = in_sizes[0] / C;                 // 100000
  int rpb = (N + G4 - 1) / G4;             // 196

  float* ws      = (float*)d_ws;
  float* qd      = ws;                               // NQ*C
  float* M       = qd + NQ * C;                      // 16
  float* bmax    = M + 16;                           // K1B*16
  float* dsum    = bmax + K1B * 16;                  // G4*NQ
  float* pooled  = dsum + G4 * NQ;                   // C
  float* Lg      = pooled + C;                       // N*LGS
  float* partial = Lg + (size_t)N * LGS;             // G4*NQ*C (~21 MB)

  hipLaunchKernelGGL(k0_qdiff,  dim3(1),      dim3(256), 0, stream, Q, qd);
  hipLaunchKernelGGL(k1_logits, dim3(K1B),    dim3(256), 0, stream, X, qd, Lg, bmax, N);
  hipLaunchKernelGGL(k2_gmax,   dim3(NQ),     dim3(256), 0, stream, bmax, M, K1B);
  hipLaunchKernelGGL(k4_partial,dim3(G4),     dim3(256), 0, stream, X, Lg, M, partial, dsum, N, rpb);
  hipLaunchKernelGGL(k5a_pooled,dim3(C / 4),  dim3(256), 0, stream, partial, dsum, pooled);
  hipLaunchKernelGGL(k5b_out,   dim3(C / 32), dim3(256), 0, stream, W, b, pooled, out);
}